// Round 1
// baseline (993.632 us; speedup 1.0000x reference)
//
#include <hip/hip_runtime.h>
#include <hip/hip_bf16.h>
#include <cstdint>

#define TN 8192
#define DN 1024
#define HN 4096
#define EN 8
#define PADMAX 17408  // 136*128 worst-case padded pair count

typedef __attribute__((ext_vector_type(8))) short short8;
typedef __attribute__((ext_vector_type(4))) float f32x4;
typedef __attribute__((ext_vector_type(4))) unsigned short ushort4v;

__device__ inline unsigned short f2bf(float f) {
  unsigned u = __builtin_bit_cast(unsigned, f);
  u = u + 0x7fffu + ((u >> 16) & 1u);
  return (unsigned short)(u >> 16);
}

__device__ inline void gload_lds16(const void* g, void* l) {
  __builtin_amdgcn_global_load_lds(
      (const __attribute__((address_space(1))) unsigned int*)g,
      (__attribute__((address_space(3))) unsigned int*)l, 16, 0, 0);
}

__global__ __launch_bounds__(256) void cvt_bf16_k(const float* __restrict__ src,
                                                  unsigned short* __restrict__ dst,
                                                  long n4) {
  long i = (long)blockIdx.x * blockDim.x + threadIdx.x;
  long stride = (long)gridDim.x * blockDim.x;
  for (; i < n4; i += stride) {
    float4 v = ((const float4*)src)[i];
    ushort4v o;
    o.x = f2bf(v.x); o.y = f2bf(v.y); o.z = f2bf(v.z); o.w = f2bf(v.w);
    ((ushort4v*)dst)[i] = o;
  }
}

// one wave per token: 8 logits via strided dot + butterfly reduce; softmax; top-2
__global__ __launch_bounds__(256) void router_k(const float* __restrict__ x,
                                                const float* __restrict__ rw,
                                                int* __restrict__ eids,
                                                float* __restrict__ wts,
                                                int* __restrict__ cnt) {
  int wid = threadIdx.x >> 6, lane = threadIdx.x & 63;
  int t = blockIdx.x * 4 + wid;
  const float* xr = x + (long)t * DN;
  float a[EN];
#pragma unroll
  for (int e = 0; e < EN; ++e) a[e] = 0.f;
  for (int k = lane; k < DN; k += 64) {
    float xv = xr[k];
#pragma unroll
    for (int e = 0; e < EN; ++e) a[e] += xv * rw[e * DN + k];
  }
#pragma unroll
  for (int off = 32; off > 0; off >>= 1) {
#pragma unroll
    for (int e = 0; e < EN; ++e) a[e] += __shfl_xor(a[e], off);
  }
  if (lane == 0) {
    float mx = a[0];
#pragma unroll
    for (int e = 1; e < EN; ++e) mx = fmaxf(mx, a[e]);
    float p[EN], s = 0.f;
#pragma unroll
    for (int e = 0; e < EN; ++e) { p[e] = expf(a[e] - mx); s += p[e]; }
    int e0 = 0; float b0 = p[0];
#pragma unroll
    for (int e = 1; e < EN; ++e) if (p[e] > b0) { b0 = p[e]; e0 = e; }
    int e1 = -1; float b1 = -1.f;
#pragma unroll
    for (int e = 0; e < EN; ++e) if (e != e0 && p[e] > b1) { b1 = p[e]; e1 = e; }
    float inv = 1.f / s;
    eids[2 * t] = e0; eids[2 * t + 1] = e1;
    wts[2 * t] = b0 * inv; wts[2 * t + 1] = b1 * inv;
    atomicAdd(&cnt[e0], 1);
    atomicAdd(&cnt[e1], 1);
  }
}

__global__ void offsets_k(const int* __restrict__ cnt, int* __restrict__ poff) {
  if (threadIdx.x == 0 && blockIdx.x == 0) {
    int o = 0;
    for (int e = 0; e < EN; ++e) { poff[e] = o; o += (cnt[e] + 127) & ~127; }
    poff[EN] = o;
  }
}

__global__ __launch_bounds__(256) void scatter_k(const int* __restrict__ eids,
                                                 const float* __restrict__ wts,
                                                 const int* __restrict__ poff,
                                                 int* __restrict__ cursor,
                                                 int* __restrict__ pairTok,
                                                 float* __restrict__ pairW) {
  int t = blockIdx.x * 256 + threadIdx.x;
#pragma unroll
  for (int k = 0; k < 2; ++k) {
    int e = eids[2 * t + k];
    int p = atomicAdd(&cursor[e], 1);
    int pos = poff[e] + p;
    pairTok[pos] = t;
    pairW[pos] = wts[2 * t + k];
  }
}

// MODE 1: h = gelu(x_gathered @ w1[e]^T)   A=xb (gather via pairTok), K=1024, N=4096
// MODE 2: out += w * (h @ w2[e]^T)         A=hb (chunk-local rows),   K=4096, N=1024
// 128x128 tile, BK=64, 4 waves (2x2), 16x16x32 bf16 MFMA, XOR-swizzled LDS
// (linear global_load_lds dest + inverse-swizzled global source + swizzled ds_read).
template <int MODE, bool BBF16>
__global__ __launch_bounds__(256) void moe_gemm_k(
    const unsigned short* __restrict__ Ab, const void* __restrict__ Bsrc,
    void* __restrict__ OutP, const int* __restrict__ pairTok,
    const float* __restrict__ pairW, const int* __restrict__ poff, int chunkStart) {
  constexpr int KDIM = (MODE == 1) ? DN : HN;
  constexpr int NDIM = (MODE == 1) ? HN : DN;
  int tileStart = chunkStart + blockIdx.y * 128;
  int Ppad = poff[EN];
  if (tileStart >= Ppad) return;
  int e = 0;
  while (tileStart >= poff[e + 1]) ++e;

  __shared__ unsigned short As[128 * 64];
  __shared__ unsigned short Bs[128 * 64];

  int tid = threadIdx.x;
  int wid = tid >> 6, lane = tid & 63;
  int waveM = wid >> 1, waveN = wid & 1;
  int tileN = blockIdx.x * 128;

  const char* aSrc[4];
  const char* bSrc[4];
#pragma unroll
  for (int i = 0; i < 4; ++i) {
    int q = i * 256 + tid;
    int row = q >> 3, sl = q & 7;
    int s = sl ^ (row & 7);  // inverse-swizzled source slot
    long aRowBase;
    if (MODE == 1) {
      int tok = pairTok[tileStart + row];
      if (tok < 0) tok = 0;  // padding row: load valid data, discard at store
      aRowBase = (long)tok * KDIM;
    } else {
      aRowBase = (long)(tileStart - chunkStart + row) * KDIM;
    }
    aSrc[i] = (const char*)(Ab + aRowBase + s * 8);
    long bRowBase = (long)e * NDIM * KDIM + (long)(tileN + row) * KDIM + s * 8;
    bSrc[i] = (const char*)Bsrc + bRowBase * (BBF16 ? 2 : 4);
  }

  f32x4 acc[4][4];
#pragma unroll
  for (int m = 0; m < 4; ++m)
#pragma unroll
    for (int n = 0; n < 4; ++n) acc[m][n] = (f32x4){0.f, 0.f, 0.f, 0.f};

  for (int k0 = 0; k0 < KDIM; k0 += 64) {
#pragma unroll
    for (int i = 0; i < 4; ++i)
      gload_lds16(aSrc[i] + (long)k0 * 2, (char*)As + (i * 256 + wid * 64) * 16);
    if (BBF16) {
#pragma unroll
      for (int i = 0; i < 4; ++i)
        gload_lds16(bSrc[i] + (long)k0 * 2, (char*)Bs + (i * 256 + wid * 64) * 16);
    } else {
#pragma unroll
      for (int i = 0; i < 4; ++i) {
        const float4* pf = (const float4*)(bSrc[i] + (long)k0 * 4);
        float4 v0 = pf[0], v1 = pf[1];
        short8 pk;
        pk[0] = (short)f2bf(v0.x); pk[1] = (short)f2bf(v0.y);
        pk[2] = (short)f2bf(v0.z); pk[3] = (short)f2bf(v0.w);
        pk[4] = (short)f2bf(v1.x); pk[5] = (short)f2bf(v1.y);
        pk[6] = (short)f2bf(v1.z); pk[7] = (short)f2bf(v1.w);
        *(short8*)((char*)Bs + (i * 256 + tid) * 16) = pk;
      }
    }
    __syncthreads();
#pragma unroll
    for (int ks = 0; ks < 2; ++ks) {
      short8 af[4], bfr[4];
#pragma unroll
      for (int m = 0; m < 4; ++m) {
        int r = waveM * 64 + m * 16 + (lane & 15);
        int slot = ks * 4 + (lane >> 4);
        af[m] = *(const short8*)((const char*)As + r * 128 + ((slot ^ (r & 7)) * 16));
      }
#pragma unroll
      for (int n = 0; n < 4; ++n) {
        int r = waveN * 64 + n * 16 + (lane & 15);
        int slot = ks * 4 + (lane >> 4);
        bfr[n] = *(const short8*)((const char*)Bs + r * 128 + ((slot ^ (r & 7)) * 16));
      }
#pragma unroll
      for (int m = 0; m < 4; ++m)
#pragma unroll
        for (int n = 0; n < 4; ++n)
          acc[m][n] = __builtin_amdgcn_mfma_f32_16x16x32_bf16(af[m], bfr[n], acc[m][n], 0, 0, 0);
    }
    __syncthreads();
  }

  if (MODE == 1) {
    unsigned short* hb = (unsigned short*)OutP;
    int rl0 = tileStart - chunkStart + waveM * 64;
#pragma unroll
    for (int m = 0; m < 4; ++m) {
#pragma unroll
      for (int r = 0; r < 4; ++r) {
        int rl = rl0 + m * 16 + (lane >> 4) * 4 + r;
#pragma unroll
        for (int n = 0; n < 4; ++n) {
          int col = tileN + waveN * 64 + n * 16 + (lane & 15);
          float v = acc[m][n][r];
          float g = 0.5f * v * (1.f + erff(v * 0.70710678118f));
          hb[(long)rl * HN + col] = f2bf(g);
        }
      }
    }
  } else {
    float* outF = (float*)OutP;
#pragma unroll
    for (int m = 0; m < 4; ++m) {
#pragma unroll
      for (int r = 0; r < 4; ++r) {
        int p = tileStart + waveM * 64 + m * 16 + (lane >> 4) * 4 + r;
        int tok = pairTok[p];
        if (tok < 0) continue;
        float wv = pairW[p];
#pragma unroll
        for (int n = 0; n < 4; ++n) {
          int col = tileN + waveN * 64 + n * 16 + (lane & 15);
          atomicAdd(&outF[(long)tok * DN + col], wv * acc[m][n][r]);
        }
      }
    }
  }
}

extern "C" void kernel_launch(void* const* d_in, const int* in_sizes, int n_in,
                              void* d_out, int out_size, void* d_ws, size_t ws_size,
                              hipStream_t stream) {
  const float* x = (const float*)d_in[0];
  const float* rw = (const float*)d_in[1];
  const float* w1 = (const float*)d_in[2];
  const float* w2 = (const float*)d_in[3];
  char* W = (char*)d_ws;
  size_t off = 0;
  auto alloc = [&](size_t sz) {
    off = (off + 255) & ~(size_t)255;
    size_t r = off; off += sz; return r;
  };
  size_t ctrlO = alloc(256);                       // cnt[8], cursor[8], poff[9]
  size_t eidsO = alloc((size_t)TN * 2 * 4);
  size_t wtsO  = alloc((size_t)TN * 2 * 4);
  size_t ptokO = alloc((size_t)PADMAX * 4);
  size_t pwO   = alloc((size_t)PADMAX * 4);
  size_t xbO   = alloc((size_t)TN * DN * 2);
  size_t wB = (size_t)EN * HN * DN * 2;
  size_t afterFixed = (off + 255) & ~(size_t)255;
  bool bw = ws_size >= afterFixed + 2 * wB + (size_t)128 * HN * 2 + 4096;
  size_t w1bO = 0, w2bO = 0;
  if (bw) { w1bO = alloc(wB); w2bO = alloc(wB); }
  size_t hbase = (off + 255) & ~(size_t)255;
  size_t avail = ws_size > hbase ? ws_size - hbase : (size_t)128 * HN * 2;
  long Cl = (long)(avail / ((size_t)HN * 2));
  if (Cl > PADMAX) Cl = PADMAX;
  Cl &= ~127l;
  if (Cl < 128) Cl = 128;
  int C = (int)Cl;
  size_t hbO = alloc((size_t)C * HN * 2);
  int nCh = (PADMAX + C - 1) / C;

  int* cnt = (int*)(W + ctrlO);
  int* cursor = cnt + 8;
  int* poff = cnt + 16;
  int* eids = (int*)(W + eidsO);
  float* wts = (float*)(W + wtsO);
  int* pairTok = (int*)(W + ptokO);
  float* pairW = (float*)(W + pwO);
  unsigned short* xb = (unsigned short*)(W + xbO);
  unsigned short* hb = (unsigned short*)(W + hbO);

  hipMemsetAsync(W + ctrlO, 0, 256, stream);
  hipMemsetAsync(W + ptokO, 0xFF, (size_t)PADMAX * 4, stream);  // pairTok = -1
  hipMemsetAsync(d_out, 0, (size_t)TN * DN * 4, stream);

  cvt_bf16_k<<<1024, 256, 0, stream>>>(x, xb, (long)TN * DN / 4);
  if (bw) {
    cvt_bf16_k<<<2048, 256, 0, stream>>>(w1, (unsigned short*)(W + w1bO), (long)EN * HN * DN / 4);
    cvt_bf16_k<<<2048, 256, 0, stream>>>(w2, (unsigned short*)(W + w2bO), (long)EN * HN * DN / 4);
  }
  router_k<<<TN / 4, 256, 0, stream>>>(x, rw, eids, wts, cnt);
  offsets_k<<<1, 1, 0, stream>>>(cnt, poff);
  scatter_k<<<TN / 256, 256, 0, stream>>>(eids, wts, poff, cursor, pairTok, pairW);

  int Ctiles = C / 128;
  for (int c = 0; c < nCh; ++c) {
    int cs = c * C;
    if (bw) {
      moe_gemm_k<1, true><<<dim3(HN / 128, Ctiles), 256, 0, stream>>>(
          xb, W + w1bO, hb, pairTok, pairW, poff, cs);
      moe_gemm_k<2, true><<<dim3(DN / 128, Ctiles), 256, 0, stream>>>(
          hb, W + w2bO, d_out, pairTok, pairW, poff, cs);
    } else {
      moe_gemm_k<1, false><<<dim3(HN / 128, Ctiles), 256, 0, stream>>>(
          xb, w1, hb, pairTok, pairW, poff, cs);
      moe_gemm_k<2, false><<<dim3(DN / 128, Ctiles), 256, 0, stream>>>(
          hb, w2, d_out, pairTok, pairW, poff, cs);
    }
  }
}

// Round 2
// 854.878 us; speedup vs baseline: 1.1623x; 1.1623x over previous
//
#include <hip/hip_runtime.h>
#include <hip/hip_bf16.h>
#include <cstdint>

#define TN 8192
#define DN 1024
#define HN 4096
#define EN 8
#define PADMAX 18432  // 72*256: 16384 pairs + 8*255 worst-case pad, rounded to 256

typedef __attribute__((ext_vector_type(8))) short short8;
typedef __attribute__((ext_vector_type(4))) float f32x4;
typedef __attribute__((ext_vector_type(4))) unsigned short ushort4v;

__device__ inline unsigned short f2bf(float f) {
  unsigned u = __builtin_bit_cast(unsigned, f);
  u = u + 0x7fffu + ((u >> 16) & 1u);
  return (unsigned short)(u >> 16);
}

__device__ inline float gelu_f(float v) {
  float z = 0.7978845608028654f * (v + 0.044715f * v * v * v);
  float ez = __expf(2.f * z);
  float th = 1.f - 2.f / (ez + 1.f);
  return 0.5f * v * (1.f + th);
}

__device__ inline void gload_lds16(const void* g, void* l) {
  __builtin_amdgcn_global_load_lds(
      (const __attribute__((address_space(1))) unsigned int*)g,
      (__attribute__((address_space(3))) unsigned int*)l, 16, 0, 0);
}

__global__ __launch_bounds__(256) void cvt_bf16_k(const float* __restrict__ src,
                                                  unsigned short* __restrict__ dst,
                                                  long n4) {
  long i = (long)blockIdx.x * blockDim.x + threadIdx.x;
  long stride = (long)gridDim.x * blockDim.x;
  for (; i < n4; i += stride) {
    float4 v = ((const float4*)src)[i];
    ushort4v o;
    o.x = f2bf(v.x); o.y = f2bf(v.y); o.z = f2bf(v.z); o.w = f2bf(v.w);
    ((ushort4v*)dst)[i] = o;
  }
}

__global__ __launch_bounds__(256) void router_k(const float* __restrict__ x,
                                                const float* __restrict__ rw,
                                                int* __restrict__ eids,
                                                float* __restrict__ wts,
                                                int* __restrict__ cnt) {
  int wid = threadIdx.x >> 6, lane = threadIdx.x & 63;
  int t = blockIdx.x * 4 + wid;
  const float* xr = x + (long)t * DN;
  float a[EN];
#pragma unroll
  for (int e = 0; e < EN; ++e) a[e] = 0.f;
  for (int k = lane; k < DN; k += 64) {
    float xv = xr[k];
#pragma unroll
    for (int e = 0; e < EN; ++e) a[e] += xv * rw[e * DN + k];
  }
#pragma unroll
  for (int off = 32; off > 0; off >>= 1) {
#pragma unroll
    for (int e = 0; e < EN; ++e) a[e] += __shfl_xor(a[e], off);
  }
  if (lane == 0) {
    float mx = a[0];
#pragma unroll
    for (int e = 1; e < EN; ++e) mx = fmaxf(mx, a[e]);
    float p[EN], s = 0.f;
#pragma unroll
    for (int e = 0; e < EN; ++e) { p[e] = __expf(a[e] - mx); s += p[e]; }
    int e0 = 0; float b0 = p[0];
#pragma unroll
    for (int e = 1; e < EN; ++e) if (p[e] > b0) { b0 = p[e]; e0 = e; }
    int e1 = -1; float b1 = -1.f;
#pragma unroll
    for (int e = 0; e < EN; ++e) if (e != e0 && p[e] > b1) { b1 = p[e]; e1 = e; }
    float inv = 1.f / s;
    eids[2 * t] = e0; eids[2 * t + 1] = e1;
    wts[2 * t] = b0 * inv; wts[2 * t + 1] = b1 * inv;
    atomicAdd(&cnt[e0], 1);
    atomicAdd(&cnt[e1], 1);
  }
}

__global__ void offsets_k(const int* __restrict__ cnt, int* __restrict__ poff) {
  if (threadIdx.x == 0 && blockIdx.x == 0) {
    int o = 0;
    for (int e = 0; e < EN; ++e) { poff[e] = o; o += (cnt[e] + 255) & ~255; }
    poff[EN] = o;
  }
}

__global__ __launch_bounds__(256) void scatter_k(const int* __restrict__ eids,
                                                 const float* __restrict__ wts,
                                                 const int* __restrict__ poff,
                                                 int* __restrict__ cursor,
                                                 int* __restrict__ pairTok,
                                                 float* __restrict__ pairW) {
  int t = blockIdx.x * 256 + threadIdx.x;
#pragma unroll
  for (int k = 0; k < 2; ++k) {
    int e = eids[2 * t + k];
    int p = atomicAdd(&cursor[e], 1);
    int pos = poff[e] + p;
    pairTok[pos] = t;
    pairW[pos] = wts[2 * t + k];
  }
}

// ---- 256x256 8-phase GEMM (T1+T2+T3+T4+T5) ----
// MODE 1: h = gelu(x_gathered @ w1[e]^T)  K=1024, N=4096, SPLIT=1
// MODE 2: out += w * (h @ w2[e]^T)        K=4096, N=1024, SPLIT=2 (grid.z)
// 512 thr = 8 waves (2M x 4N), BK=64, LDS 128KiB (A/B x 2 halves x dbuf),
// XOR slot-swizzle (slot ^ (row&7)) via pre-swizzled global source + swizzled ds_read.
// Staging per tile t: ph1 B0(t+1)->other buf, ph2 B1(t+1)->other buf,
// ph4 A0,A1(t+2)->current buf A region (dead after ph3 barrier).
// vmcnt(4) at tile end only (A(t+2) stays in flight); drain for last 2 tiles.

#define BAR() { __builtin_amdgcn_s_barrier(); __builtin_amdgcn_sched_barrier(0); }

#define LDA(QM, PAR) { const char* _b = smem + (PAR)*32768 + waveM*16384;            \
  _Pragma("unroll") for (int m = 0; m < 4; ++m) {                                    \
    int row = ((QM)*4 + m)*16 + (lane & 15); int cb = row * 128;                     \
    a[m][0] = *(const short8*)(_b + cb + (((lane>>4) ^ (row&7)) * 16));              \
    a[m][1] = *(const short8*)(_b + cb + (((4 + (lane>>4)) ^ (row&7)) * 16)); } }

#define LDB(PAR) { const char* _b = smem + 65536 + (PAR)*32768 + (waveN>>1)*16384;   \
  _Pragma("unroll") for (int n = 0; n < 4; ++n) {                                    \
    int row = (waveN&1)*64 + n*16 + (lane & 15); int cb = row * 128;                 \
    b[n][0] = *(const short8*)(_b + cb + (((lane>>4) ^ (row&7)) * 16));              \
    b[n][1] = *(const short8*)(_b + cb + (((4 + (lane>>4)) ^ (row&7)) * 16)); } }

#define MM(QM, QN) { __builtin_amdgcn_s_setprio(1);                                  \
  _Pragma("unroll") for (int m = 0; m < 4; ++m)                                      \
    _Pragma("unroll") for (int n = 0; n < 2; ++n) {                                  \
      acc[(QM)*4+m][(QN)*2+n] = __builtin_amdgcn_mfma_f32_16x16x32_bf16(             \
          a[m][0], b[(QN)*2+n][0], acc[(QM)*4+m][(QN)*2+n], 0, 0, 0);                \
      acc[(QM)*4+m][(QN)*2+n] = __builtin_amdgcn_mfma_f32_16x16x32_bf16(             \
          a[m][1], b[(QN)*2+n][1], acc[(QM)*4+m][(QN)*2+n], 0, 0, 0); }              \
  __builtin_amdgcn_s_setprio(0); }

template <int MODE, bool BBF16>
__global__ __launch_bounds__(512, 2) void moe_gemm256_k(
    const unsigned short* __restrict__ Ab, const void* __restrict__ Bsrc,
    void* __restrict__ OutP, const int* __restrict__ pairTok,
    const float* __restrict__ pairW, const int* __restrict__ poff, int chunkStart) {
  constexpr int KD = (MODE == 1) ? DN : HN;
  constexpr int ND = (MODE == 1) ? HN : DN;
  constexpr int SPLIT = (MODE == 1) ? 1 : 2;
  constexpr int KLEN = KD / SPLIT;
  constexpr int NT = KLEN / 64;

  extern __shared__ char smem[];

  // T1: bijective XCD swizzle over (x,y)
  int NX = gridDim.x;
  int NXY = NX * gridDim.y;
  int orig = blockIdx.y * NX + blockIdx.x;
  int qq = NXY >> 3, rrm = NXY & 7;
  int xcd = orig & 7, pos = orig >> 3;
  int wg = (xcd < rrm ? xcd * (qq + 1) : rrm * (qq + 1) + (xcd - rrm) * qq) + pos;
  int tileN = (wg % NX) * 256;
  int tileStart = chunkStart + (wg / NX) * 256;

  int Ppad = poff[EN];
  if (tileStart >= Ppad) return;
  int e = 0;
  while (e < EN - 1 && tileStart >= poff[e + 1]) ++e;

  int tid = threadIdx.x;
  int wid = tid >> 6, lane = tid & 63;
  int waveM = wid >> 2, waveN = wid & 3;
  int kbase = blockIdx.z * KLEN;

  // staging source pointers: load j covers q = j*512+tid -> row q>>3, lin slot q&7
  int r0 = tid >> 3, s0 = (tid & 7) ^ (r0 & 7);
  int r1 = 64 + r0;
  int s1 = (tid & 7) ^ (r1 & 7);  // == s0 (64 % 8 == 0), kept for clarity
  const char* aSrc[2][2];
  const char* bSrc[2][2];
#pragma unroll
  for (int h = 0; h < 2; ++h) {
    int rh0 = h * 128 + r0, rh1 = h * 128 + r1;
    long ar0, ar1;
    if (MODE == 1) {
      int t0 = pairTok[tileStart + rh0]; if (t0 < 0) t0 = 0;
      int t1 = pairTok[tileStart + rh1]; if (t1 < 0) t1 = 0;
      ar0 = (long)t0 * KD; ar1 = (long)t1 * KD;
    } else {
      ar0 = (long)(tileStart - chunkStart + rh0) * KD;
      ar1 = (long)(tileStart - chunkStart + rh1) * KD;
    }
    aSrc[h][0] = (const char*)(Ab + ar0 + kbase + s0 * 8);
    aSrc[h][1] = (const char*)(Ab + ar1 + kbase + s1 * 8);
    long bb0 = (long)e * ND * KD + (long)(tileN + rh0) * KD + kbase + s0 * 8;
    long bb1 = (long)e * ND * KD + (long)(tileN + rh1) * KD + kbase + s1 * 8;
    bSrc[h][0] = (const char*)Bsrc + bb0 * (BBF16 ? 2 : 4);
    bSrc[h][1] = (const char*)Bsrc + bb1 * (BBF16 ? 2 : 4);
  }

  auto stageA = [&](int k0, int dstPar, int h) {
    char* d = smem + dstPar * 32768 + h * 16384 + wid * 1024;
    gload_lds16(aSrc[h][0] + (long)k0 * 2, d);
    gload_lds16(aSrc[h][1] + (long)k0 * 2, d + 8192);
  };
  auto stageB = [&](int k0, int dstPar, int h) {
    if constexpr (BBF16) {
      char* d = smem + 65536 + dstPar * 32768 + h * 16384 + wid * 1024;
      gload_lds16(bSrc[h][0] + (long)k0 * 2, d);
      gload_lds16(bSrc[h][1] + (long)k0 * 2, d + 8192);
    } else {
      char* d = smem + 65536 + dstPar * 32768 + h * 16384 + tid * 16;
#pragma unroll
      for (int j = 0; j < 2; ++j) {
        const float4* pf = (const float4*)(bSrc[h][j] + (long)k0 * 4);
        float4 v0 = pf[0], v1 = pf[1];
        short8 pk;
        pk[0] = (short)f2bf(v0.x); pk[1] = (short)f2bf(v0.y);
        pk[2] = (short)f2bf(v0.z); pk[3] = (short)f2bf(v0.w);
        pk[4] = (short)f2bf(v1.x); pk[5] = (short)f2bf(v1.y);
        pk[6] = (short)f2bf(v1.z); pk[7] = (short)f2bf(v1.w);
        *(short8*)(d + j * 8192) = pk;
      }
    }
  };

  f32x4 acc[8][4];
#pragma unroll
  for (int m = 0; m < 8; ++m)
#pragma unroll
    for (int n = 0; n < 4; ++n) acc[m][n] = (f32x4){0.f, 0.f, 0.f, 0.f};
  short8 a[4][2], b[4][2];

  // prologue: A(t0), B(t0), A(t1); counted wait leaves A(t1) in flight
  stageA(0, 0, 0); stageA(0, 0, 1);
  stageB(0, 0, 0); stageB(0, 0, 1);
  stageA(64, 1, 0); stageA(64, 1, 1);
  if constexpr (BBF16) {
    asm volatile("s_waitcnt vmcnt(4)" ::: "memory");
  } else {
    asm volatile("s_waitcnt vmcnt(4) lgkmcnt(0)" ::: "memory");
  }
  BAR();

  for (int t = 0; t < NT; ++t) {
    int par = t & 1;
    int kN1 = (t + 1) * 64, kN2 = (t + 2) * 64;
    // ph1
    if (t + 1 < NT) stageB(kN1, par ^ 1, 0);
    LDA(0, par); LDB(par);
    BAR();
    MM(0, 0);
    BAR();
    // ph2
    if (t + 1 < NT) stageB(kN1, par ^ 1, 1);
    MM(0, 1);
    BAR();
    // ph3
    LDA(1, par);
    BAR();
    MM(1, 0);
    BAR();
    // ph4
    if (t + 2 < NT) { stageA(kN2, par, 0); stageA(kN2, par, 1); }
    MM(1, 1);
    if constexpr (!BBF16) asm volatile("s_waitcnt lgkmcnt(0)" ::: "memory");
    if (t + 2 < NT) {
      asm volatile("s_waitcnt vmcnt(4)" ::: "memory");
    } else {
      asm volatile("s_waitcnt vmcnt(0)" ::: "memory");
    }
    BAR();
  }

  if (MODE == 1) {
    unsigned short* hbp = (unsigned short*)OutP;
    int rl0 = tileStart - chunkStart + waveM * 128;
#pragma unroll
    for (int m = 0; m < 8; ++m) {
#pragma unroll
      for (int r = 0; r < 4; ++r) {
        int rl = rl0 + m * 16 + (lane >> 4) * 4 + r;
#pragma unroll
        for (int n = 0; n < 4; ++n) {
          int col = tileN + waveN * 64 + n * 16 + (lane & 15);
          hbp[(long)rl * HN + col] = f2bf(gelu_f(acc[m][n][r]));
        }
      }
    }
  } else {
    float* outF = (float*)OutP;
#pragma unroll
    for (int m = 0; m < 8; ++m) {
#pragma unroll
      for (int r = 0; r < 4; ++r) {
        int p = tileStart + waveM * 128 + m * 16 + (lane >> 4) * 4 + r;
        int tok = pairTok[p];
        if (tok < 0) continue;
        float wv = pairW[p];
#pragma unroll
        for (int n = 0; n < 4; ++n) {
          int col = tileN + waveN * 64 + n * 16 + (lane & 15);
          atomicAdd(&outF[(long)tok * DN + col], wv * acc[m][n][r]);
        }
      }
    }
  }
}

extern "C" void kernel_launch(void* const* d_in, const int* in_sizes, int n_in,
                              void* d_out, int out_size, void* d_ws, size_t ws_size,
                              hipStream_t stream) {
  const float* x = (const float*)d_in[0];
  const float* rw = (const float*)d_in[1];
  const float* w1 = (const float*)d_in[2];
  const float* w2 = (const float*)d_in[3];
  char* W = (char*)d_ws;
  size_t off = 0;
  auto alloc = [&](size_t sz) {
    off = (off + 255) & ~(size_t)255;
    size_t r = off; off += sz; return r;
  };
  size_t ctrlO = alloc(256);  // cnt[8], cursor[8], poff[9]
  size_t eidsO = alloc((size_t)TN * 2 * 4);
  size_t wtsO  = alloc((size_t)TN * 2 * 4);
  size_t ptokO = alloc((size_t)PADMAX * 4);
  size_t pwO   = alloc((size_t)PADMAX * 4);
  size_t xbO   = alloc((size_t)TN * DN * 2);
  size_t wB = (size_t)EN * HN * DN * 2;
  size_t afterFixed = (off + 255) & ~(size_t)255;
  bool bw = ws_size >= afterFixed + 2 * wB + (size_t)256 * HN * 2 + 4096;
  size_t w1bO = 0, w2bO = 0;
  if (bw) { w1bO = alloc(wB); w2bO = alloc(wB); }
  size_t hbase = (off + 255) & ~(size_t)255;
  size_t avail = ws_size > hbase ? ws_size - hbase : (size_t)256 * HN * 2;
  long Cl = (long)(avail / ((size_t)HN * 2));
  if (Cl > PADMAX) Cl = PADMAX;
  Cl &= ~255l;
  if (Cl < 256) Cl = 256;
  int C = (int)Cl;
  size_t hbO = alloc((size_t)C * HN * 2);
  int nCh = (PADMAX + C - 1) / C;

  int* cnt = (int*)(W + ctrlO);
  int* cursor = cnt + 8;
  int* poff = cnt + 16;
  int* eids = (int*)(W + eidsO);
  float* wts = (float*)(W + wtsO);
  int* pairTok = (int*)(W + ptokO);
  float* pairW = (float*)(W + pwO);
  unsigned short* xb = (unsigned short*)(W + xbO);
  unsigned short* hb = (unsigned short*)(W + hbO);

  hipFuncSetAttribute(reinterpret_cast<const void*>(moe_gemm256_k<1, true>),
                      hipFuncAttributeMaxDynamicSharedMemorySize, 131072);
  hipFuncSetAttribute(reinterpret_cast<const void*>(moe_gemm256_k<2, true>),
                      hipFuncAttributeMaxDynamicSharedMemorySize, 131072);
  hipFuncSetAttribute(reinterpret_cast<const void*>(moe_gemm256_k<1, false>),
                      hipFuncAttributeMaxDynamicSharedMemorySize, 131072);
  hipFuncSetAttribute(reinterpret_cast<const void*>(moe_gemm256_k<2, false>),
                      hipFuncAttributeMaxDynamicSharedMemorySize, 131072);

  hipMemsetAsync(W + ctrlO, 0, 256, stream);
  hipMemsetAsync(W + ptokO, 0xFF, (size_t)PADMAX * 4, stream);  // pairTok = -1
  hipMemsetAsync(d_out, 0, (size_t)TN * DN * 4, stream);

  cvt_bf16_k<<<1024, 256, 0, stream>>>(x, xb, (long)TN * DN / 4);
  if (bw) {
    cvt_bf16_k<<<2048, 256, 0, stream>>>(w1, (unsigned short*)(W + w1bO), (long)EN * HN * DN / 4);
    cvt_bf16_k<<<2048, 256, 0, stream>>>(w2, (unsigned short*)(W + w2bO), (long)EN * HN * DN / 4);
  }
  router_k<<<TN / 4, 256, 0, stream>>>(x, rw, eids, wts, cnt);
  offsets_k<<<1, 1, 0, stream>>>(cnt, poff);
  scatter_k<<<TN / 256, 256, 0, stream>>>(eids, wts, poff, cursor, pairTok, pairW);

  int Ctiles = C / 256;
  for (int c = 0; c < nCh; ++c) {
    int cs = c * C;
    if (bw) {
      moe_gemm256_k<1, true><<<dim3(HN / 256, Ctiles, 1), 512, 131072, stream>>>(
          xb, W + w1bO, hb, pairTok, pairW, poff, cs);
      moe_gemm256_k<2, true><<<dim3(DN / 256, Ctiles, 2), 512, 131072, stream>>>(
          hb, W + w2bO, d_out, pairTok, pairW, poff, cs);
    } else {
      moe_gemm256_k<1, false><<<dim3(HN / 256, Ctiles, 1), 512, 131072, stream>>>(
          xb, w1, hb, pairTok, pairW, poff, cs);
      moe_gemm256_k<2, false><<<dim3(DN / 256, Ctiles, 2), 512, 131072, stream>>>(
          hb, w2, d_out, pairTok, pairW, poff, cs);
    }
  }
}

// Round 3
// 849.522 us; speedup vs baseline: 1.1696x; 1.0063x over previous
//
#include <hip/hip_runtime.h>
#include <hip/hip_bf16.h>
#include <cstdint>

#define TN 8192
#define DN 1024
#define HN 4096
#define EN 8
#define PADMAX 18432  // 72*256: 16384 pairs + 8*255 worst-case pad, rounded to 256

typedef __attribute__((ext_vector_type(8))) short short8;
typedef __attribute__((ext_vector_type(4))) float f32x4;
typedef __attribute__((ext_vector_type(4))) unsigned short ushort4v;

__device__ inline unsigned short f2bf(float f) {
  unsigned u = __builtin_bit_cast(unsigned, f);
  u = u + 0x7fffu + ((u >> 16) & 1u);
  return (unsigned short)(u >> 16);
}

__device__ inline float gelu_f(float v) {
  float z = 0.7978845608028654f * (v + 0.044715f * v * v * v);
  float ez = __expf(2.f * z);
  float th = 1.f - 2.f / (ez + 1.f);
  return 0.5f * v * (1.f + th);
}

__device__ inline void gload_lds16(const void* g, void* l) {
  __builtin_amdgcn_global_load_lds(
      (const __attribute__((address_space(1))) unsigned int*)g,
      (__attribute__((address_space(3))) unsigned int*)l, 16, 0, 0);
}

__global__ __launch_bounds__(256) void cvt_bf16_k(const float* __restrict__ src,
                                                  unsigned short* __restrict__ dst,
                                                  long n4) {
  long i = (long)blockIdx.x * blockDim.x + threadIdx.x;
  long stride = (long)gridDim.x * blockDim.x;
  for (; i < n4; i += stride) {
    float4 v = ((const float4*)src)[i];
    ushort4v o;
    o.x = f2bf(v.x); o.y = f2bf(v.y); o.z = f2bf(v.z); o.w = f2bf(v.w);
    ((ushort4v*)dst)[i] = o;
  }
}

__global__ __launch_bounds__(256) void router_k(const float* __restrict__ x,
                                                const float* __restrict__ rw,
                                                int* __restrict__ eids,
                                                float* __restrict__ wts,
                                                int* __restrict__ cnt) {
  int wid = threadIdx.x >> 6, lane = threadIdx.x & 63;
  int t = blockIdx.x * 4 + wid;
  const float* xr = x + (long)t * DN;
  float a[EN];
#pragma unroll
  for (int e = 0; e < EN; ++e) a[e] = 0.f;
  for (int k = lane; k < DN; k += 64) {
    float xv = xr[k];
#pragma unroll
    for (int e = 0; e < EN; ++e) a[e] += xv * rw[e * DN + k];
  }
#pragma unroll
  for (int off = 32; off > 0; off >>= 1) {
#pragma unroll
    for (int e = 0; e < EN; ++e) a[e] += __shfl_xor(a[e], off);
  }
  if (lane == 0) {
    float mx = a[0];
#pragma unroll
    for (int e = 1; e < EN; ++e) mx = fmaxf(mx, a[e]);
    float p[EN], s = 0.f;
#pragma unroll
    for (int e = 0; e < EN; ++e) { p[e] = __expf(a[e] - mx); s += p[e]; }
    int e0 = 0; float b0 = p[0];
#pragma unroll
    for (int e = 1; e < EN; ++e) if (p[e] > b0) { b0 = p[e]; e0 = e; }
    int e1 = -1; float b1 = -1.f;
#pragma unroll
    for (int e = 0; e < EN; ++e) if (e != e0 && p[e] > b1) { b1 = p[e]; e1 = e; }
    float inv = 1.f / s;
    eids[2 * t] = e0; eids[2 * t + 1] = e1;
    wts[2 * t] = b0 * inv; wts[2 * t + 1] = b1 * inv;
    atomicAdd(&cnt[e0], 1);
    atomicAdd(&cnt[e1], 1);
  }
}

__global__ void offsets_k(const int* __restrict__ cnt, int* __restrict__ poff) {
  if (threadIdx.x == 0 && blockIdx.x == 0) {
    int o = 0;
    for (int e = 0; e < EN; ++e) { poff[e] = o; o += (cnt[e] + 255) & ~255; }
    poff[EN] = o;
  }
}

__global__ __launch_bounds__(256) void scatter_k(const int* __restrict__ eids,
                                                 const float* __restrict__ wts,
                                                 const int* __restrict__ poff,
                                                 int* __restrict__ cursor,
                                                 int* __restrict__ pairTok,
                                                 float* __restrict__ pairW) {
  int t = blockIdx.x * 256 + threadIdx.x;
#pragma unroll
  for (int k = 0; k < 2; ++k) {
    int e = eids[2 * t + k];
    int p = atomicAdd(&cursor[e], 1);
    int pos = poff[e] + p;
    pairTok[pos] = t;
    pairW[pos] = wts[2 * t + k];
  }
}

// ---- 256x256 4-phase-per-K-tile GEMM (m201-style: T1+T2+T3+T4+T5) ----
// 512 thr = 8 waves (2M x 4N); per-wave output 128x64. BK=64, LDS 128KiB:
// buf P: A = P*32768 + half*16384 (half=waveM), B = 65536 + P*32768 + half*16384.
// Phase = {ds_reads for this quadrant | stage 1 half-tile} bar; lgkm0; 16 MFMA; bar.
// Stage pattern per tile t: ph1 (t+1).A0, ph2 (t+1).A1, ph3 (t+2).B0, ph4 (t+2).B1.
// vmcnt(4) once per tile (ph4 end): (t+1).A* landed, (t+2).B* stay in flight.

#define BAR() { __builtin_amdgcn_s_barrier(); __builtin_amdgcn_sched_barrier(0); }
#define LGKM0() { asm volatile("s_waitcnt lgkmcnt(0)" ::: "memory"); \
                  __builtin_amdgcn_sched_barrier(0); }

#define LDA_H(QM, PAR) { const char* _b = smem + (PAR)*32768 + waveM*16384;          \
  _Pragma("unroll") for (int m = 0; m < 4; ++m) {                                    \
    int row = ((QM)*4 + m)*16 + (lane & 15); int cb = row * 128;                     \
    a[m][0] = *(const short8*)(_b + cb + (((lane>>4) ^ (row&7)) * 16));              \
    a[m][1] = *(const short8*)(_b + cb + (((4 + (lane>>4)) ^ (row&7)) * 16)); } }

#define LDB_H(NH, PAR) { const char* _b = smem + 65536 + (PAR)*32768 + (waveN>>1)*16384; \
  _Pragma("unroll") for (int n = 0; n < 2; ++n) {                                    \
    int row = (waveN&1)*64 + ((NH)*2+n)*16 + (lane & 15); int cb = row * 128;        \
    b[(NH)*2+n][0] = *(const short8*)(_b + cb + (((lane>>4) ^ (row&7)) * 16));       \
    b[(NH)*2+n][1] = *(const short8*)(_b + cb + (((4 + (lane>>4)) ^ (row&7)) * 16)); } }

#define MM16(QM, NH) { __builtin_amdgcn_s_setprio(1);                                \
  _Pragma("unroll") for (int m = 0; m < 4; ++m)                                      \
    _Pragma("unroll") for (int n = 0; n < 2; ++n) {                                  \
      acc[(QM)*4+m][(NH)*2+n] = __builtin_amdgcn_mfma_f32_16x16x32_bf16(             \
          a[m][0], b[(NH)*2+n][0], acc[(QM)*4+m][(NH)*2+n], 0, 0, 0);                \
      acc[(QM)*4+m][(NH)*2+n] = __builtin_amdgcn_mfma_f32_16x16x32_bf16(             \
          a[m][1], b[(NH)*2+n][1], acc[(QM)*4+m][(NH)*2+n], 0, 0, 0); }              \
  __builtin_amdgcn_s_setprio(0); }

template <int MODE, bool BBF16>
__global__ __launch_bounds__(512, 2) void moe_gemm256_k(
    const unsigned short* __restrict__ Ab, const void* __restrict__ Bsrc,
    void* __restrict__ OutP, const int* __restrict__ pairTok,
    const float* __restrict__ pairW, const int* __restrict__ poff, int chunkStart) {
  constexpr int KD = (MODE == 1) ? DN : HN;
  constexpr int ND = (MODE == 1) ? HN : DN;
  constexpr int SPLIT = (MODE == 1) ? 1 : 2;
  constexpr int KLEN = KD / SPLIT;
  constexpr int NT = KLEN / 64;

  extern __shared__ char smem[];

  // T1: bijective XCD swizzle over (x,y)
  int NX = gridDim.x;
  int NXY = NX * gridDim.y;
  int orig = blockIdx.y * NX + blockIdx.x;
  int qq = NXY >> 3, rrm = NXY & 7;
  int xcd = orig & 7, pos = orig >> 3;
  int wg = (xcd < rrm ? xcd * (qq + 1) : rrm * (qq + 1) + (xcd - rrm) * qq) + pos;
  int tileN = (wg % NX) * 256;
  int tileStart = chunkStart + (wg / NX) * 256;

  int Ppad = poff[EN];
  if (tileStart >= Ppad) return;
  int e = 0;
  while (e < EN - 1 && tileStart >= poff[e + 1]) ++e;

  int tid = threadIdx.x;
  int wid = tid >> 6, lane = tid & 63;
  int waveM = wid >> 2, waveN = wid & 3;
  int kbase = blockIdx.z * KLEN;

  // staging sources: load j covers q = j*512+tid -> row q>>3, linear slot q&7,
  // global slot s = (q&7)^(row&7)  (inverse swizzle so LDS linear dest works)
  int r0 = tid >> 3, s0 = (tid & 7) ^ (r0 & 7);
  const char* aSrc[2][2];
  const char* bSrc[2][2];
#pragma unroll
  for (int h = 0; h < 2; ++h) {
    int rh0 = h * 128 + r0, rh1 = h * 128 + 64 + r0;
    long ar0, ar1;
    if (MODE == 1) {
      int t0 = pairTok[tileStart + rh0]; if (t0 < 0) t0 = 0;
      int t1 = pairTok[tileStart + rh1]; if (t1 < 0) t1 = 0;
      ar0 = (long)t0 * KD; ar1 = (long)t1 * KD;
    } else {
      ar0 = (long)(tileStart - chunkStart + rh0) * KD;
      ar1 = (long)(tileStart - chunkStart + rh1) * KD;
    }
    aSrc[h][0] = (const char*)(Ab + ar0 + kbase + s0 * 8);
    aSrc[h][1] = (const char*)(Ab + ar1 + kbase + s0 * 8);
    long bb0 = (long)e * ND * KD + (long)(tileN + rh0) * KD + kbase + s0 * 8;
    long bb1 = (long)e * ND * KD + (long)(tileN + rh1) * KD + kbase + s0 * 8;
    bSrc[h][0] = (const char*)Bsrc + bb0 * (BBF16 ? 2 : 4);
    bSrc[h][1] = (const char*)Bsrc + bb1 * (BBF16 ? 2 : 4);
  }

  auto stageA = [&](int k0, int dstPar, int h) {
    char* d = smem + dstPar * 32768 + h * 16384 + wid * 1024;
    gload_lds16(aSrc[h][0] + (long)k0 * 2, d);
    gload_lds16(aSrc[h][1] + (long)k0 * 2, d + 8192);
  };
  auto stageB = [&](int k0, int dstPar, int h) {
    if constexpr (BBF16) {
      char* d = smem + 65536 + dstPar * 32768 + h * 16384 + wid * 1024;
      gload_lds16(bSrc[h][0] + (long)k0 * 2, d);
      gload_lds16(bSrc[h][1] + (long)k0 * 2, d + 8192);
    } else {
      char* d = smem + 65536 + dstPar * 32768 + h * 16384 + tid * 16;
#pragma unroll
      for (int j = 0; j < 2; ++j) {
        const float4* pf = (const float4*)(bSrc[h][j] + (long)k0 * 4);
        float4 v0 = pf[0], v1 = pf[1];
        short8 pk;
        pk[0] = (short)f2bf(v0.x); pk[1] = (short)f2bf(v0.y);
        pk[2] = (short)f2bf(v0.z); pk[3] = (short)f2bf(v0.w);
        pk[4] = (short)f2bf(v1.x); pk[5] = (short)f2bf(v1.y);
        pk[6] = (short)f2bf(v1.z); pk[7] = (short)f2bf(v1.w);
        *(short8*)(d + j * 8192) = pk;
      }
    }
  };

  f32x4 acc[8][4];
#pragma unroll
  for (int m = 0; m < 8; ++m)
#pragma unroll
    for (int n = 0; n < 4; ++n) acc[m][n] = (f32x4){0.f, 0.f, 0.f, 0.f};
  short8 a[4][2], b[4][2];

  // prologue: tile0 {A0,A1,B0,B1} -> buf0, tile1 {B0,B1} -> buf1.
  // tile1 A staged during tile0 ph1/ph2 (steady-state pattern).
  stageA(0, 0, 0); stageA(0, 0, 1);
  stageB(0, 0, 0); stageB(0, 0, 1);
  stageB(64, 1, 0); stageB(64, 1, 1);
  if constexpr (BBF16) {
    asm volatile("s_waitcnt vmcnt(4)" ::: "memory");
  } else {
    asm volatile("s_waitcnt vmcnt(0) lgkmcnt(0)" ::: "memory");
  }
  BAR();

  for (int t = 0; t < NT; ++t) {
    int P = t & 1;
    int k1 = (t + 1) * 64, k2 = (t + 2) * 64;
    // ph1: Q(M0,N0)
    LDA_H(0, P); LDB_H(0, P);
    if (t + 1 < NT) stageA(k1, P ^ 1, 0);
    BAR(); LGKM0();
    MM16(0, 0);
    BAR();
    // ph2: Q(M0,N1)
    LDB_H(1, P);
    if (t + 1 < NT) stageA(k1, P ^ 1, 1);
    BAR(); LGKM0();
    MM16(0, 1);
    BAR();
    // ph3: Q(M1,N0)
    LDA_H(1, P);
    if (t + 2 < NT) stageB(k2, P, 0);
    BAR(); LGKM0();
    MM16(1, 0);
    BAR();
    // ph4: Q(M1,N1)
    if (t + 2 < NT) stageB(k2, P, 1);
    BAR();
    MM16(1, 1);
    if (BBF16 && t + 2 < NT) {
      asm volatile("s_waitcnt vmcnt(4)" ::: "memory");
    } else {
      asm volatile("s_waitcnt vmcnt(0)" ::: "memory");
    }
    BAR();
  }

  if (MODE == 1) {
    unsigned short* hbp = (unsigned short*)OutP;
    int rl0 = tileStart - chunkStart + waveM * 128;
#pragma unroll
    for (int m = 0; m < 8; ++m) {
#pragma unroll
      for (int r = 0; r < 4; ++r) {
        int rl = rl0 + m * 16 + (lane >> 4) * 4 + r;
#pragma unroll
        for (int n = 0; n < 4; ++n) {
          int col = tileN + waveN * 64 + n * 16 + (lane & 15);
          hbp[(long)rl * HN + col] = f2bf(gelu_f(acc[m][n][r]));
        }
      }
    }
  } else {
    float* outF = (float*)OutP;
#pragma unroll
    for (int m = 0; m < 8; ++m) {
#pragma unroll
      for (int r = 0; r < 4; ++r) {
        int p = tileStart + waveM * 128 + m * 16 + (lane >> 4) * 4 + r;
        int tok = pairTok[p];
        if (tok < 0) continue;
        float wv = pairW[p];
#pragma unroll
        for (int n = 0; n < 4; ++n) {
          int col = tileN + waveN * 64 + n * 16 + (lane & 15);
          atomicAdd(&outF[(long)tok * DN + col], wv * acc[m][n][r]);
        }
      }
    }
  }
}

extern "C" void kernel_launch(void* const* d_in, const int* in_sizes, int n_in,
                              void* d_out, int out_size, void* d_ws, size_t ws_size,
                              hipStream_t stream) {
  const float* x = (const float*)d_in[0];
  const float* rw = (const float*)d_in[1];
  const float* w1 = (const float*)d_in[2];
  const float* w2 = (const float*)d_in[3];
  char* W = (char*)d_ws;
  size_t off = 0;
  auto alloc = [&](size_t sz) {
    off = (off + 255) & ~(size_t)255;
    size_t r = off; off += sz; return r;
  };
  size_t ctrlO = alloc(256);  // cnt[8], cursor[8], poff[9]
  size_t eidsO = alloc((size_t)TN * 2 * 4);
  size_t wtsO  = alloc((size_t)TN * 2 * 4);
  size_t ptokO = alloc((size_t)PADMAX * 4);
  size_t pwO   = alloc((size_t)PADMAX * 4);
  size_t xbO   = alloc((size_t)TN * DN * 2);
  size_t wB = (size_t)EN * HN * DN * 2;
  size_t afterFixed = (off + 255) & ~(size_t)255;
  bool bw = ws_size >= afterFixed + 2 * wB + (size_t)256 * HN * 2 + 4096;
  size_t w1bO = 0, w2bO = 0;
  if (bw) { w1bO = alloc(wB); w2bO = alloc(wB); }
  size_t hbase = (off + 255) & ~(size_t)255;
  size_t avail = ws_size > hbase ? ws_size - hbase : (size_t)256 * HN * 2;
  long Cl = (long)(avail / ((size_t)HN * 2));
  if (Cl > PADMAX) Cl = PADMAX;
  Cl &= ~255l;
  if (Cl < 256) Cl = 256;
  int C = (int)Cl;
  size_t hbO = alloc((size_t)C * HN * 2);
  int nCh = (PADMAX + C - 1) / C;

  int* cnt = (int*)(W + ctrlO);
  int* cursor = cnt + 8;
  int* poff = cnt + 16;
  int* eids = (int*)(W + eidsO);
  float* wts = (float*)(W + wtsO);
  int* pairTok = (int*)(W + ptokO);
  float* pairW = (float*)(W + pwO);
  unsigned short* xb = (unsigned short*)(W + xbO);
  unsigned short* hb = (unsigned short*)(W + hbO);

  hipFuncSetAttribute(reinterpret_cast<const void*>(moe_gemm256_k<1, true>),
                      hipFuncAttributeMaxDynamicSharedMemorySize, 131072);
  hipFuncSetAttribute(reinterpret_cast<const void*>(moe_gemm256_k<2, true>),
                      hipFuncAttributeMaxDynamicSharedMemorySize, 131072);
  hipFuncSetAttribute(reinterpret_cast<const void*>(moe_gemm256_k<1, false>),
                      hipFuncAttributeMaxDynamicSharedMemorySize, 131072);
  hipFuncSetAttribute(reinterpret_cast<const void*>(moe_gemm256_k<2, false>),
                      hipFuncAttributeMaxDynamicSharedMemorySize, 131072);

  hipMemsetAsync(W + ctrlO, 0, 256, stream);
  hipMemsetAsync(W + ptokO, 0xFF, (size_t)PADMAX * 4, stream);  // pairTok = -1
  hipMemsetAsync(d_out, 0, (size_t)TN * DN * 4, stream);

  cvt_bf16_k<<<1024, 256, 0, stream>>>(x, xb, (long)TN * DN / 4);
  if (bw) {
    cvt_bf16_k<<<2048, 256, 0, stream>>>(w1, (unsigned short*)(W + w1bO), (long)EN * HN * DN / 4);
    cvt_bf16_k<<<2048, 256, 0, stream>>>(w2, (unsigned short*)(W + w2bO), (long)EN * HN * DN / 4);
  }
  router_k<<<TN / 4, 256, 0, stream>>>(x, rw, eids, wts, cnt);
  offsets_k<<<1, 1, 0, stream>>>(cnt, poff);
  scatter_k<<<TN / 256, 256, 0, stream>>>(eids, wts, poff, cursor, pairTok, pairW);

  int Ctiles = C / 256;
  for (int c = 0; c < nCh; ++c) {
    int cs = c * C;
    if (bw) {
      moe_gemm256_k<1, true><<<dim3(HN / 256, Ctiles, 1), 512, 131072, stream>>>(
          xb, W + w1bO, hb, pairTok, pairW, poff, cs);
      moe_gemm256_k<2, true><<<dim3(DN / 256, Ctiles, 2), 512, 131072, stream>>>(
          hb, W + w2bO, d_out, pairTok, pairW, poff, cs);
    } else {
      moe_gemm256_k<1, false><<<dim3(HN / 256, Ctiles, 1), 512, 131072, stream>>>(
          xb, w1, hb, pairTok, pairW, poff, cs);
      moe_gemm256_k<2, false><<<dim3(DN / 256, Ctiles, 2), 512, 131072, stream>>>(
          hb, w2, d_out, pairTok, pairW, poff, cs);
    }
  }
}